// Round 5
// baseline (291.785 us; speedup 1.0000x reference)
//
#include <hip/hip_runtime.h>

// HybridQLSTMQuantum, fused single kernel, MI355X — v5: register-resident W,
// k-split workers, priority recurrence wave.
//
// qgate identity (verified analytically):
//   qgate(angles)[w] = prod_{j<=w} cos(angles[j])
//
// R4 post-mortem: phase A was L1-gather-bound — with lane=o, every w-load
// instruction touches 32 distinct W rows (32 cache lines), re-fetched per
// dot (~65K line-gathers/chunk). Fix: W slices live in registers, loaded
// ONCE per kernel; k-dim split across 4 worker waves.
//
// v5 structure: one block per batch row b, grid=256, block=320 (5 waves).
//   wave 0 lanes 0-31: 256-step recurrence (s_setprio(1)); per step sums 4
//     k-partials (prefetched one step ahead).
//   waves 1-4 (kv=0..3): own k in [kv*64, kv*64+64). Per chunk of 32 t:
//     lane = o(0..31) x th(0..1); th-half handles 16 t's. W slice: 16 float4
//     in VGPRs (persistent). X loads wave-uniform per th-half (broadcast-
//     coalesced, each X element fetched once). Partials -> As4[buf][kv][t][o].
//   Double-buffered As4; one uniform __syncthreads per chunk.
// Runtime dtype sniff retained (bf16 path mirrors f32 path).
// All parameter loads sanitized: NaN output impossible by construction.

#define S_LEN 256
#define BATCH 256
#define DIMK  256
#define FAN   264
#define CHUNK 32
#define NCH   8      // S_LEN / CHUNK
#define NKV   4      // k-split across worker waves
#define TPB   320    // 5 waves

__device__ __forceinline__ float lo16f(unsigned u) {
    union { unsigned u; float f; } v; v.u = u << 16; return v.f;
}
__device__ __forceinline__ float hi16f(unsigned u) {
    union { unsigned u; float f; } v; v.u = u & 0xffff0000u; return v.f;
}
__device__ __forceinline__ float b2f(unsigned short u) {
    union { unsigned u; float f; } v; v.u = ((unsigned)u) << 16; return v.f;
}
__device__ __forceinline__ unsigned short f2b(float f) {
    union { float f; unsigned u; } v; v.f = f;
    unsigned r = v.u + 0x7fffu + ((v.u >> 16) & 1u);  // RNE
    return (unsigned short)(r >> 16);
}
__device__ __forceinline__ float sane(float x) {
    return (__builtin_fabsf(x) < 1e30f) ? x : 0.f;   // NaN compares false -> 0
}
__device__ __forceinline__ float ldE(const void* p, int idx, bool f32) {
    return f32 ? ((const float*)p)[idx] : b2f(((const unsigned short*)p)[idx]);
}
__device__ __forceinline__ void stE(void* p, long idx, float v, bool f32) {
    if (f32) ((float*)p)[idx] = v;
    else     ((unsigned short*)p)[idx] = f2b(v);
}

// DPP row_shr:K within 16-lane rows (CTRL = 0x110|K); invalid lanes keep old.
template<int CTRL>
__device__ __forceinline__ float dpp_f(float x) {
    int xi = __builtin_bit_cast(int, x);
    int r = __builtin_amdgcn_update_dpp(xi, xi, CTRL, 0xF, 0xF, false);
    return __builtin_bit_cast(float, r);
}
// ds_swizzle BitMode: src_lane = ((lane & and) | or) ^ xor, imm = xor<<10|or<<5|and
template<int IMM>
__device__ __forceinline__ float swz_f(float x) {
    return __builtin_bit_cast(float,
        __builtin_amdgcn_ds_swizzle(__builtin_bit_cast(int, x), IMM));
}
__device__ __forceinline__ float rdlane_f(float x, int l) {
    return __builtin_bit_cast(float,
        __builtin_amdgcn_readlane(__builtin_bit_cast(int, x), l));
}

__global__ __launch_bounds__(TPB) void qlstm_fused(
    const void* __restrict__ X,  const void* __restrict__ hx, const void* __restrict__ cx,
    const void* __restrict__ Wf, const void* __restrict__ bf_,
    const void* __restrict__ Wi, const void* __restrict__ bi_,
    const void* __restrict__ Wu, const void* __restrict__ bu_,
    const void* __restrict__ Wo, const void* __restrict__ bo_,
    const void* __restrict__ tf, const void* __restrict__ ti,
    const void* __restrict__ tu, const void* __restrict__ to_,
    void* __restrict__ out)
{
    __shared__ float As4[2][NKV][CHUNK][32];   // 32 KiB: k-partials, dbuf
    __shared__ int s_isf32;

    const int tid = threadIdx.x;
    const int b   = blockIdx.x;

    // ---- dtype sniff: bf16 storage -> even-index ushorts are bf16 of N(0,1)
    // (exponent near 127); fp32 -> low mantissa bits, exponent-field uniform.
    if (tid == 0) {
        const unsigned short* u = (const unsigned short*)X;
        int hits = 0;
        for (int i = 0; i < 64; ++i) {
            int e = (u[2 * i] >> 7) & 0xFF;
            if (e >= 110 && e <= 135) ++hits;
        }
        s_isf32 = (hits < 32) ? 1 : 0;
    }
    __syncthreads();
    const bool f32 = (s_isf32 != 0);

    const int wv   = tid >> 6;      // wave 0 = recurrence, 1..4 = workers
    const int lane = tid & 63;
    const int kv   = wv - 1;        // worker k-slice index (0..3)
    const int o    = lane & 31;
    const int th   = lane >> 5;     // t-half within worker wave
    const int g    = o >> 3, w = o & 7;
    const void* Wg = (g == 0) ? Wf : (g == 1) ? Wi : (g == 2) ? Wu : Wo;

    // ---- persistent W slice in registers (workers only; loaded ONCE)
    float4 wreg[16];
    uint4  wbreg[8];
    if (wv >= 1) {
        if (f32) {
            const float4* wr =
                (const float4*)((const float*)Wg + w * FAN + kv * 64);
#pragma unroll
            for (int i = 0; i < 16; ++i) wreg[i] = wr[i];
        } else {
            const uint4* wr =
                (const uint4*)((const unsigned short*)Wg + w * FAN + kv * 64);
#pragma unroll
            for (int i = 0; i < 8; ++i) wbreg[i] = wr[i];
        }
    }

    // ---- chunk fill (workers): partial dots over k-slice kv, all 32 t's
    auto fill = [&](int ch) {
        float (*dst)[32] = As4[ch & 1][kv];
        const int tb = ch * CHUNK + th * 16;
        if (f32) {
            for (int j = 0; j < 16; ++j) {
                const float4* xr = (const float4*)((const float*)X
                        + ((long)(tb + j) * BATCH + b) * DIMK + kv * 64);
                float a0 = 0.f, a1 = 0.f, a2 = 0.f, a3 = 0.f;
#pragma unroll
                for (int i = 0; i < 16; ++i) {
                    float4 xu = xr[i];
                    a0 = fmaf(xu.x, wreg[i].x, a0);
                    a1 = fmaf(xu.y, wreg[i].y, a1);
                    a2 = fmaf(xu.z, wreg[i].z, a2);
                    a3 = fmaf(xu.w, wreg[i].w, a3);
                }
                dst[th * 16 + j][o] = sane((a0 + a1) + (a2 + a3));
            }
        } else {
            for (int j = 0; j < 16; ++j) {
                const uint4* xr = (const uint4*)((const unsigned short*)X
                        + ((long)(tb + j) * BATCH + b) * DIMK + kv * 64);
                float a0 = 0.f, a1 = 0.f, a2 = 0.f, a3 = 0.f;
#pragma unroll
                for (int i = 0; i < 8; ++i) {
                    uint4 xu = xr[i], wu = wbreg[i];
                    a0 = fmaf(lo16f(xu.x), lo16f(wu.x), a0);
                    a1 = fmaf(hi16f(xu.x), hi16f(wu.x), a1);
                    a2 = fmaf(lo16f(xu.y), lo16f(wu.y), a2);
                    a3 = fmaf(hi16f(xu.y), hi16f(wu.y), a3);
                    a0 = fmaf(lo16f(xu.z), lo16f(wu.z), a0);
                    a1 = fmaf(hi16f(xu.z), hi16f(wu.z), a1);
                    a2 = fmaf(lo16f(xu.w), lo16f(wu.w), a2);
                    a3 = fmaf(hi16f(xu.w), hi16f(wu.w), a3);
                }
                dst[th * 16 + j][o] = sane((a0 + a1) + (a2 + a3));
            }
        }
    };

    // ---- recurrence state (lanes 0..31 of wave 0)
    float Wh[8];
    float bt = 0.f, h = 0.f, c = 0.f, qv = 1.f;
    int rw = 0, rg = 0;
    if (tid < 32) {
        rw = tid & 7; rg = tid >> 3;
        const void* bg = (rg == 0) ? bf_ : (rg == 1) ? bi_ : (rg == 2) ? bu_ : bo_;
        const void* tg = (rg == 0) ? tf  : (rg == 1) ? ti  : (rg == 2) ? tu  : to_;
        const int wr = rw * FAN;
#pragma unroll
        for (int j = 0; j < 8; ++j)
            Wh[j] = sane(ldE(Wg, wr + DIMK + j, f32));   // Wg: g==rg here
        bt = sane(ldE(bg, rw, f32)) + sane(ldE(tg, rw, f32));
        h  = sane(ldE(hx, b * 8 + rw, f32));
        c  = sane(ldE(cx, b * 8 + rw, f32));
        qv = (rg == 2) ? 2.f : 1.f;   // 1 -> sigmoid, 2 -> tanh (unified form)
    }
    if (wv == 0) __builtin_amdgcn_s_setprio(1);   // favor the serial chain

    // ---- prologue: workers fill chunk 0
    if (wv >= 1) fill(0);
    __syncthreads();

    // ---- pipelined main loop
    for (int ch = 0; ch < NCH; ++ch) {
        if (wv >= 1 && ch + 1 < NCH) fill(ch + 1);
        if (tid < 32) {
            const int buf = ch & 1;
            float n0 = As4[buf][0][0][tid], n1 = As4[buf][1][0][tid];
            float n2 = As4[buf][2][0][tid], n3 = As4[buf][3][0][tid];
            float a_cur = (n0 + n1) + (n2 + n3);
            for (int s = 0; s < CHUNK; ++s) {
                const int sn = (s < CHUNK - 1) ? s + 1 : s;
                // prefetch next step's partials (hidden under this step)
                float m0 = As4[buf][0][sn][tid], m1 = As4[buf][1][sn][tid];
                float m2 = As4[buf][2][sn][tid], m3 = As4[buf][3][sn][tid];

                // h-dot via v_readlane (h replicated across gate groups)
                float d0 = 0.f, d1 = 0.f;
#pragma unroll
                for (int j = 0; j < 8; j += 2) {
                    d0 = fmaf(rdlane_f(h, j),     Wh[j],     d0);
                    d1 = fmaf(rdlane_f(h, j + 1), Wh[j + 1], d1);
                }
                float ang = a_cur + bt + (d0 + d1);
                float e = __cosf(ang);

                // inclusive cumprod over 8-lane group via DPP row_shr
                { float v = dpp_f<0x111>(e); e = (rw >= 1) ? e * v : e; }
                { float v = dpp_f<0x112>(e); e = (rw >= 2) ? e * v : e; }
                { float v = dpp_f<0x114>(e); e = (rw >= 4) ? e * v : e; }

                // own-gate nonlinearity: 1 - q/(exp(q*E)+1); q=1 sigm, q=2 tanh
                float ez  = __expf(qv * e);
                float val = 1.f - __fdividef(qv, ez + 1.f);

                // gather the 4 transformed gates for this wire (one LDS round)
                float fg = swz_f<0x007>(val);          // lane  w
                float ig = swz_f<0x107>(val);          // lane  8+w
                float ug = swz_f<0x207>(val);          // lane 16+w
                float og = swz_f<0x307>(val);          // lane 24+w

                c = fmaf(fg, c, ig * ug);
                float e2 = __expf(2.f * c);
                float th2 = 1.f - __fdividef(2.f, e2 + 1.f);
                h = og * th2;

                if (rg == 0)
                    stE(out, (long)(ch * CHUNK + s) * 2048 + b * 8 + rw, h, f32);
                a_cur = (m0 + m1) + (m2 + m3);
            }
        }
        __syncthreads();   // uniform: every thread reaches it each chunk
    }

    if (tid < 32 && rg == 0) {
        stE(out, 524288L + b * 8 + rw, h, f32);   // hT
        stE(out, 526336L + b * 8 + rw, c, f32);   // cT
    }
}

extern "C" void kernel_launch(void* const* d_in, const int* in_sizes, int n_in,
                              void* d_out, int out_size, void* d_ws, size_t ws_size,
                              hipStream_t stream) {
    qlstm_fused<<<dim3(BATCH), dim3(TPB), 0, stream>>>(
        d_in[0], d_in[1], d_in[2],
        d_in[3], d_in[4], d_in[5], d_in[6],
        d_in[7], d_in[8], d_in[9], d_in[10],
        d_in[11], d_in[12], d_in[13], d_in[14],
        d_out);
}

// Round 6
// 213.925 us; speedup vs baseline: 1.3640x; 1.3640x over previous
//
#include <hip/hip_runtime.h>

// HybridQLSTMQuantum, fused single kernel, MI355X — v6: spill-free
// register-resident W (unified f32 storage), k-split workers.
//
// qgate identity (verified analytically):
//   qgate(angles)[w] = prod_{j<=w} cos(angles[j])
//
// R5 post-mortem: FETCH 33->154MB, WRITE 2->67MB, VGPR pinned at 128 =
// scratch spills. Dual-dtype W arrays (64+32 VGPRs) + default launch_bounds
// register cap spilled the "persistent" W slices; every chunk re-read them
// from scratch. v6: ONE float4 wreg[16] (bf16 unpacked to f32 once at load,
// W is persistent so unpack is one-time), and __launch_bounds__(TPB, 1) to
// lift the VGPR cap (occupancy is 5 waves/CU by design; spills matter more).
//
// Structure: one block per batch row b, grid=256, block=320 (5 waves).
//   wave 0 lanes 0-31: 256-step recurrence (s_setprio(1)); per step sums 4
//     k-partials (prefetched one step ahead).
//   waves 1-4 (kv=0..3): own k in [kv*64, kv*64+64). Per chunk of 32 t:
//     lane = o(0..31) x th(0..1); th-half handles 16 t's. W slice persistent
//     in VGPRs. X loads wave-uniform per th-half (broadcast-coalesced).
//     Partials -> As4[buf][kv][t][o]. Double-buffered; one barrier per chunk.
// Runtime dtype sniff retained. All parameter loads sanitized.

#define S_LEN 256
#define BATCH 256
#define DIMK  256
#define FAN   264
#define CHUNK 32
#define NCH   8      // S_LEN / CHUNK
#define NKV   4      // k-split across worker waves
#define TPB   320    // 5 waves

__device__ __forceinline__ float lo16f(unsigned u) {
    union { unsigned u; float f; } v; v.u = u << 16; return v.f;
}
__device__ __forceinline__ float hi16f(unsigned u) {
    union { unsigned u; float f; } v; v.u = u & 0xffff0000u; return v.f;
}
__device__ __forceinline__ float b2f(unsigned short u) {
    union { unsigned u; float f; } v; v.u = ((unsigned)u) << 16; return v.f;
}
__device__ __forceinline__ unsigned short f2b(float f) {
    union { float f; unsigned u; } v; v.f = f;
    unsigned r = v.u + 0x7fffu + ((v.u >> 16) & 1u);  // RNE
    return (unsigned short)(r >> 16);
}
__device__ __forceinline__ float sane(float x) {
    return (__builtin_fabsf(x) < 1e30f) ? x : 0.f;   // NaN compares false -> 0
}
__device__ __forceinline__ float ldE(const void* p, int idx, bool f32) {
    return f32 ? ((const float*)p)[idx] : b2f(((const unsigned short*)p)[idx]);
}
__device__ __forceinline__ void stE(void* p, long idx, float v, bool f32) {
    if (f32) ((float*)p)[idx] = v;
    else     ((unsigned short*)p)[idx] = f2b(v);
}

// DPP row_shr:K within 16-lane rows (CTRL = 0x110|K); invalid lanes keep old.
template<int CTRL>
__device__ __forceinline__ float dpp_f(float x) {
    int xi = __builtin_bit_cast(int, x);
    int r = __builtin_amdgcn_update_dpp(xi, xi, CTRL, 0xF, 0xF, false);
    return __builtin_bit_cast(float, r);
}
// ds_swizzle BitMode: src_lane = ((lane & and) | or) ^ xor, imm = xor<<10|or<<5|and
template<int IMM>
__device__ __forceinline__ float swz_f(float x) {
    return __builtin_bit_cast(float,
        __builtin_amdgcn_ds_swizzle(__builtin_bit_cast(int, x), IMM));
}
__device__ __forceinline__ float rdlane_f(float x, int l) {
    return __builtin_bit_cast(float,
        __builtin_amdgcn_readlane(__builtin_bit_cast(int, x), l));
}

__global__ __launch_bounds__(TPB, 1) void qlstm_fused(
    const void* __restrict__ X,  const void* __restrict__ hx, const void* __restrict__ cx,
    const void* __restrict__ Wf, const void* __restrict__ bf_,
    const void* __restrict__ Wi, const void* __restrict__ bi_,
    const void* __restrict__ Wu, const void* __restrict__ bu_,
    const void* __restrict__ Wo, const void* __restrict__ bo_,
    const void* __restrict__ tf, const void* __restrict__ ti,
    const void* __restrict__ tu, const void* __restrict__ to_,
    void* __restrict__ out)
{
    __shared__ float As4[2][NKV][CHUNK][32];   // 32 KiB: k-partials, dbuf
    __shared__ int s_isf32;

    const int tid = threadIdx.x;
    const int b   = blockIdx.x;

    // ---- dtype sniff: bf16 storage -> even-index ushorts are bf16 of N(0,1)
    // (exponent near 127); fp32 -> low mantissa bits, exponent-field uniform.
    if (tid == 0) {
        const unsigned short* u = (const unsigned short*)X;
        int hits = 0;
        for (int i = 0; i < 64; ++i) {
            int e = (u[2 * i] >> 7) & 0xFF;
            if (e >= 110 && e <= 135) ++hits;
        }
        s_isf32 = (hits < 32) ? 1 : 0;
    }
    __syncthreads();
    const bool f32 = (s_isf32 != 0);

    const int wv   = tid >> 6;      // wave 0 = recurrence, 1..4 = workers
    const int lane = tid & 63;
    const int kv   = wv - 1;        // worker k-slice index (0..3)
    const int o    = lane & 31;
    const int th   = lane >> 5;     // t-half within worker wave
    const int g    = o >> 3, w = o & 7;
    const void* Wg = (g == 0) ? Wf : (g == 1) ? Wi : (g == 2) ? Wu : Wo;

    // ---- persistent W slice in registers, UNIFIED f32 storage.
    // bf16 storage is unpacked to f32 once here (W persistent => one-time).
    float4 wreg[16];
    if (wv >= 1) {
        if (f32) {
            const float4* wr =
                (const float4*)((const float*)Wg + w * FAN + kv * 64);
#pragma unroll
            for (int i = 0; i < 16; ++i) wreg[i] = wr[i];
        } else {
            const uint4* wr =
                (const uint4*)((const unsigned short*)Wg + w * FAN + kv * 64);
#pragma unroll
            for (int i = 0; i < 8; ++i) {
                uint4 wu = wr[i];
                wreg[2 * i + 0] = make_float4(lo16f(wu.x), hi16f(wu.x),
                                              lo16f(wu.y), hi16f(wu.y));
                wreg[2 * i + 1] = make_float4(lo16f(wu.z), hi16f(wu.z),
                                              lo16f(wu.w), hi16f(wu.w));
            }
        }
    }

    // ---- chunk fill (workers): partial dots over k-slice kv, all 32 t's
    auto fill = [&](int ch) {
        float (*dst)[32] = As4[ch & 1][kv];
        const int tb = ch * CHUNK + th * 16;
        if (f32) {
            for (int j = 0; j < 16; ++j) {
                const float4* xr = (const float4*)((const float*)X
                        + ((long)(tb + j) * BATCH + b) * DIMK + kv * 64);
                float a0 = 0.f, a1 = 0.f, a2 = 0.f, a3 = 0.f;
#pragma unroll
                for (int i = 0; i < 16; ++i) {
                    float4 xu = xr[i];
                    a0 = fmaf(xu.x, wreg[i].x, a0);
                    a1 = fmaf(xu.y, wreg[i].y, a1);
                    a2 = fmaf(xu.z, wreg[i].z, a2);
                    a3 = fmaf(xu.w, wreg[i].w, a3);
                }
                dst[th * 16 + j][o] = sane((a0 + a1) + (a2 + a3));
            }
        } else {
            for (int j = 0; j < 16; ++j) {
                const uint4* xr = (const uint4*)((const unsigned short*)X
                        + ((long)(tb + j) * BATCH + b) * DIMK + kv * 64);
                float a0 = 0.f, a1 = 0.f, a2 = 0.f, a3 = 0.f;
#pragma unroll
                for (int i = 0; i < 8; ++i) {
                    uint4 xu = xr[i];
                    a0 = fmaf(lo16f(xu.x), wreg[2 * i].x, a0);
                    a1 = fmaf(hi16f(xu.x), wreg[2 * i].y, a1);
                    a2 = fmaf(lo16f(xu.y), wreg[2 * i].z, a2);
                    a3 = fmaf(hi16f(xu.y), wreg[2 * i].w, a3);
                    a0 = fmaf(lo16f(xu.z), wreg[2 * i + 1].x, a0);
                    a1 = fmaf(hi16f(xu.z), wreg[2 * i + 1].y, a1);
                    a2 = fmaf(lo16f(xu.w), wreg[2 * i + 1].z, a2);
                    a3 = fmaf(hi16f(xu.w), wreg[2 * i + 1].w, a3);
                }
                dst[th * 16 + j][o] = sane((a0 + a1) + (a2 + a3));
            }
        }
    };

    // ---- recurrence state (lanes 0..31 of wave 0)
    float Wh[8];
    float bt = 0.f, h = 0.f, c = 0.f, qv = 1.f;
    int rw = 0, rg = 0;
    if (tid < 32) {
        rw = tid & 7; rg = tid >> 3;
        const void* bg = (rg == 0) ? bf_ : (rg == 1) ? bi_ : (rg == 2) ? bu_ : bo_;
        const void* tg = (rg == 0) ? tf  : (rg == 1) ? ti  : (rg == 2) ? tu  : to_;
        const int wr = rw * FAN;
#pragma unroll
        for (int j = 0; j < 8; ++j)
            Wh[j] = sane(ldE(Wg, wr + DIMK + j, f32));   // Wg: g==rg here
        bt = sane(ldE(bg, rw, f32)) + sane(ldE(tg, rw, f32));
        h  = sane(ldE(hx, b * 8 + rw, f32));
        c  = sane(ldE(cx, b * 8 + rw, f32));
        qv = (rg == 2) ? 2.f : 1.f;   // 1 -> sigmoid, 2 -> tanh (unified form)
    }
    if (wv == 0) __builtin_amdgcn_s_setprio(1);   // favor the serial chain

    // ---- prologue: workers fill chunk 0
    if (wv >= 1) fill(0);
    __syncthreads();

    // ---- pipelined main loop
    for (int ch = 0; ch < NCH; ++ch) {
        if (wv >= 1 && ch + 1 < NCH) fill(ch + 1);
        if (tid < 32) {
            const int buf = ch & 1;
            float n0 = As4[buf][0][0][tid], n1 = As4[buf][1][0][tid];
            float n2 = As4[buf][2][0][tid], n3 = As4[buf][3][0][tid];
            float a_cur = (n0 + n1) + (n2 + n3);
            for (int s = 0; s < CHUNK; ++s) {
                const int sn = (s < CHUNK - 1) ? s + 1 : s;
                // prefetch next step's partials (hidden under this step)
                float m0 = As4[buf][0][sn][tid], m1 = As4[buf][1][sn][tid];
                float m2 = As4[buf][2][sn][tid], m3 = As4[buf][3][sn][tid];

                // h-dot via v_readlane (h replicated across gate groups)
                float d0 = 0.f, d1 = 0.f;
#pragma unroll
                for (int j = 0; j < 8; j += 2) {
                    d0 = fmaf(rdlane_f(h, j),     Wh[j],     d0);
                    d1 = fmaf(rdlane_f(h, j + 1), Wh[j + 1], d1);
                }
                float ang = a_cur + bt + (d0 + d1);
                float e = __cosf(ang);

                // inclusive cumprod over 8-lane group via DPP row_shr
                { float v = dpp_f<0x111>(e); e = (rw >= 1) ? e * v : e; }
                { float v = dpp_f<0x112>(e); e = (rw >= 2) ? e * v : e; }
                { float v = dpp_f<0x114>(e); e = (rw >= 4) ? e * v : e; }

                // own-gate nonlinearity: 1 - q/(exp(q*E)+1); q=1 sigm, q=2 tanh
                float ez  = __expf(qv * e);
                float val = 1.f - __fdividef(qv, ez + 1.f);

                // gather the 4 transformed gates for this wire (one LDS round)
                float fg = swz_f<0x007>(val);          // lane  w
                float ig = swz_f<0x107>(val);          // lane  8+w
                float ug = swz_f<0x207>(val);          // lane 16+w
                float og = swz_f<0x307>(val);          // lane 24+w

                c = fmaf(fg, c, ig * ug);
                float e2 = __expf(2.f * c);
                float th2 = 1.f - __fdividef(2.f, e2 + 1.f);
                h = og * th2;

                if (rg == 0)
                    stE(out, (long)(ch * CHUNK + s) * 2048 + b * 8 + rw, h, f32);
                a_cur = (m0 + m1) + (m2 + m3);
            }
        }
        __syncthreads();   // uniform: every thread reaches it each chunk
    }

    if (tid < 32 && rg == 0) {
        stE(out, 524288L + b * 8 + rw, h, f32);   // hT
        stE(out, 526336L + b * 8 + rw, c, f32);   // cT
    }
}

extern "C" void kernel_launch(void* const* d_in, const int* in_sizes, int n_in,
                              void* d_out, int out_size, void* d_ws, size_t ws_size,
                              hipStream_t stream) {
    qlstm_fused<<<dim3(BATCH), dim3(TPB), 0, stream>>>(
        d_in[0], d_in[1], d_in[2],
        d_in[3], d_in[4], d_in[5], d_in[6],
        d_in[7], d_in[8], d_in[9], d_in[10],
        d_in[11], d_in[12], d_in[13], d_in[14],
        d_out);
}